// Round 4
// baseline (115.239 us; speedup 1.0000x reference)
//
#include <hip/hip_runtime.h>

#define BATCH 2
#define H 512
#define W 512
#define CS 21
#define CI 3
#define P 256      // pixels per block (row segment)
#define TPB 256
#define NCH 6      // float4 chunks per pixel, starts {0,4,8,12,16,17}

__device__ __forceinline__ void fma4(float4& a, const float4 v, const float w) {
    a.x = fmaf(v.x, w, a.x);
    a.y = fmaf(v.y, w, a.y);
    a.z = fmaf(v.z, w, a.z);
    a.w = fmaf(v.w, w, a.w);
}

__device__ __forceinline__ void decode_item(int wi, int x0,
                                            int& p, int& om, int& oc, int& op) {
    p = wi / NCH;
    int q = wi - p * NCH;
    int coff = (q == 5) ? 17 : (q << 2);     // chunk starts 0,4,8,12,16,17
    int x  = x0 + p;
    int xm = (x == 0)     ? 1     : x - 1;
    int xp = (x == W - 1) ? W - 2 : x + 1;
    om = xm * CS + coff;
    oc = x  * CS + coff;
    op = xp * CS + coff;
}

__device__ __forceinline__ void load9(float4* v,
                                      const float* __restrict__ row0,
                                      const float* __restrict__ row1,
                                      const float* __restrict__ row2,
                                      int om, int oc, int op) {
    v[0] = *(const float4*)(row0 + om);
    v[1] = *(const float4*)(row0 + oc);
    v[2] = *(const float4*)(row0 + op);
    v[3] = *(const float4*)(row1 + om);
    v[4] = *(const float4*)(row1 + oc);
    v[5] = *(const float4*)(row1 + op);
    v[6] = *(const float4*)(row2 + om);
    v[7] = *(const float4*)(row2 + oc);
    v[8] = *(const float4*)(row2 + op);
}

// LDS: 12 KB buffer. Phase 1 uses first 2322 floats as guide tile [3][P+2][3];
// then overwritten with per-pixel normalized weights [P][12].
__global__ __launch_bounds__(TPB, 4) void jbu_kernel(
    const float* __restrict__ src, const float* __restrict__ im,
    float* __restrict__ out)
{
    __shared__ __align__(16) float s_buf[P * 12];   // 12 KB

    const int t = threadIdx.x;

    // ---- XCD-aware swizzle: XCD (f&7) owns contiguous 64-row band ----
    const int f   = blockIdx.x;          // 0..2047
    const int xcd = f & 7;
    const int g   = f >> 3;              // 0..255
    const int y   = (xcd << 6) | (g & 63);
    const int r   = g >> 6;              // 0..3
    const int x0  = (r & 1) * P;
    const int b   = r >> 1;

    const int ry0 = (y == 0)     ? 1     : y - 1;
    const int ry2 = (y == H - 1) ? H - 2 : y + 1;

    // ---- Phase 1a: stage guide tile (reflect applied at stage time) ----
    const float* imb = im + (size_t)b * H * W * CI;
    for (int i = t; i < 3 * (P + 2) * CI; i += TPB) {
        int row = i / ((P + 2) * CI);
        int rem = i - row * ((P + 2) * CI);
        int col = rem / CI;
        int ch  = rem - col * CI;
        int ry  = (row == 0) ? ry0 : ((row == 1) ? y : ry2);
        int gx  = x0 + col - 1;
        gx = (gx < 0) ? 1 : ((gx >= W) ? W - 2 : gx);
        s_buf[i] = imb[(ry * W + gx) * CI + ch];
    }
    __syncthreads();

    // ---- Phase 1b: per-pixel weights in registers, normalized ----
    float4 wa, wb;
    float w8n;
    {
        const float w1k[9] = {0.36787944f, 0.60653066f, 0.36787944f,
                              0.60653066f, 1.0f,        0.60653066f,
                              0.36787944f, 0.60653066f, 0.36787944f};
        const int cbase = ((P + 2) + t + 1) * CI;
        const float c0 = s_buf[cbase + 0];
        const float c1 = s_buf[cbase + 1];
        const float c2 = s_buf[cbase + 2];
        float wv[9];
        float den = 0.f;
        #pragma unroll
        for (int k = 0; k < 9; ++k) {
            const int dy = k / 3, dx = k % 3;
            const int idx = (dy * (P + 2) + t + dx) * CI;
            float d0 = s_buf[idx + 0] - c0;
            float d1 = s_buf[idx + 1] - c1;
            float d2 = s_buf[idx + 2] - c2;
            float w = __expf(-8.0f * (d0 * d0 + d1 * d1 + d2 * d2)) * w1k[k];
            wv[k] = w;
            den += w;
        }
        const float inv = 1.0f / den;
        wa = make_float4(wv[0] * inv, wv[1] * inv, wv[2] * inv, wv[3] * inv);
        wb = make_float4(wv[4] * inv, wv[5] * inv, wv[6] * inv, wv[7] * inv);
        w8n = wv[8] * inv;
    }
    __syncthreads();

    *(float4*)&s_buf[t * 12 + 0] = wa;
    *(float4*)&s_buf[t * 12 + 4] = wb;
    s_buf[t * 12 + 8] = w8n;
    __syncthreads();

    // ---- Phase 2: software-pipelined — prefetch iter i+1's 9 loads
    //      before computing iter i, so VMEM never idles during FMAs ----
    const float* row0 = src + (size_t)(b * H + ry0) * (W * CS);
    const float* row1 = src + (size_t)(b * H + y  ) * (W * CS);
    const float* row2 = src + (size_t)(b * H + ry2) * (W * CS);
    float*       orow = out + (size_t)(b * H + y  ) * (W * CS);

    int pC, omC, ocC, opC;
    decode_item(t, x0, pC, omC, ocC, opC);
    float4 cur[9];
    load9(cur, row0, row1, row2, omC, ocC, opC);

    #pragma unroll
    for (int it = 0; it < NCH; ++it) {
        int pN = 0, omN = 0, ocN = 0, opN = 0;
        float4 nxt[9];
        if (it < NCH - 1) {
            decode_item(t + (it + 1) * TPB, x0, pN, omN, ocN, opN);
            load9(nxt, row0, row1, row2, omN, ocN, opN);
        }

        const float4 pwA = *(const float4*)&s_buf[pC * 12 + 0];
        const float4 pwB = *(const float4*)&s_buf[pC * 12 + 4];
        const float  pw8 = s_buf[pC * 12 + 8];

        float4 acc = {0.f, 0.f, 0.f, 0.f};
        fma4(acc, cur[0], pwA.x);
        fma4(acc, cur[1], pwA.y);
        fma4(acc, cur[2], pwA.z);
        fma4(acc, cur[3], pwA.w);
        fma4(acc, cur[4], pwB.x);
        fma4(acc, cur[5], pwB.y);
        fma4(acc, cur[6], pwB.z);
        fma4(acc, cur[7], pwB.w);
        fma4(acc, cur[8], pw8);

        *(float4*)(orow + ocC) = acc;

        if (it < NCH - 1) {
            #pragma unroll
            for (int j = 0; j < 9; ++j) cur[j] = nxt[j];
            pC  = pN;
            ocC = ocN;
        }
    }
}

extern "C" void kernel_launch(void* const* d_in, const int* in_sizes, int n_in,
                              void* d_out, int out_size, void* d_ws, size_t ws_size,
                              hipStream_t stream) {
    const float* src = (const float*)d_in[0];
    const float* im  = (const float*)d_in[1];
    float* out = (float*)d_out;
    dim3 grid((W / P) * H * BATCH, 1, 1);   // 2048 blocks, swizzle-decoded in-kernel
    jbu_kernel<<<grid, TPB, 0, stream>>>(src, im, out);
}